// Round 4
// baseline (998.173 us; speedup 1.0000x reference)
//
#include <hip/hip_runtime.h>
#include <hip/hip_bf16.h>

#define NT 256
#define TB 8   // batch elements per block

typedef unsigned short u16;
typedef unsigned int u32;

__device__ __forceinline__ float bf2f(u16 u) {
  union { u32 i; float f; } v; v.i = ((u32)u) << 16; return v.f;
}
__device__ __forceinline__ float2 up2(u32 p) {
  union { u32 i; float f; } a, b;
  a.i = p << 16; b.i = p & 0xffff0000u;
  return make_float2(a.f, b.f);
}
__device__ __forceinline__ u16 f2bf(float f) {
  union { float f; u32 i; } v; v.f = f;
  u32 r = v.i + 0x7fffu + ((v.i >> 16) & 1u);  // round-to-nearest-even
  return (u16)(r >> 16);
}
__device__ __forceinline__ u32 pk2(float a, float b) {
  return (u32)f2bf(a) | ((u32)f2bf(b) << 16);
}
__device__ __forceinline__ void up8(uint4 u, float* d) {
  float2 f;
  f = up2(u.x); d[0]=f.x; d[1]=f.y;
  f = up2(u.y); d[2]=f.x; d[3]=f.y;
  f = up2(u.z); d[4]=f.x; d[5]=f.y;
  f = up2(u.w); d[6]=f.x; d[7]=f.y;
}

// prep: block-independent s1bp[a][f] = s1_b + arep @ s1w[:,128:].T  -> ws (f32)
__global__ void prep_kernel(const float* __restrict__ emb, const int* __restrict__ act_idx,
                            const int* __restrict__ act_cnt, const float* __restrict__ s1w,
                            const float* __restrict__ s1b, float* __restrict__ ws) {
  __shared__ float s_arep[20][64];
  int t = threadIdx.x;
  for (int o = t; o < 20 * 64; o += 256) {
    int a = o >> 6, k = o & 63;
    int cnt = act_cnt[a];
    float sum = 0.f;
#pragma unroll
    for (int j = 0; j < 4; ++j)
      if (j < cnt) sum += emb[act_idx[a * 4 + j] * 64 + k];
    s_arep[a][k] = sum / (float)(cnt > 1 ? cnt : 1);
  }
  __syncthreads();
  for (int o = t; o < 20 * 64; o += 256) {
    int a = o >> 6, f = o & 63;
    const float* wr = s1w + f * 192 + 128;
    float acc = s1b[f];
#pragma unroll 8
    for (int k = 0; k < 64; ++k) acc += s_arep[a][k] * wr[k];
    ws[o] = acc;
  }
}

struct SW1 {                       // attention window
  u16 x_ah[64 * 72];               // x (P0b-P1), then ah (P4-P5a)
  u16 qkv[64 * 200];               // [es][f] f: 0..63 q | 64..127 k | 128..191 v
  float sc[8 * 4 * 8 * 9];         // probs [(e*4+h)*8+q]*9+kk
};
struct SW2 {                       // post-attention window (overlays qkv+sc)
  u16 x_ah[64 * 72];               // keeps ah alive through P5a
  float hx[TB][68];
  float g1[TB][68];
  float hand[TB][68];
  float g[TB][36];
  float ctx[TB][132];
  float ctx2[TB][132];
  float s1a[TB][68];
  float w2t[64][36];               // w2t[j][m] = s2w[m][j]
};

__global__ __launch_bounds__(NT, 3) void policy_fused(
    const int* __restrict__ hand_cards, const float* __restrict__ game_state,
    const int* __restrict__ hand_size, const int* __restrict__ num_valid,
    const float* __restrict__ emb, const float* __restrict__ ipw, const float* __restrict__ ipb,
    const float* __restrict__ ow, const float* __restrict__ ob,
    const float* __restrict__ g1w, const float* __restrict__ g1b,
    const float* __restrict__ g2w, const float* __restrict__ g2b,
    const float* __restrict__ c1w, const float* __restrict__ c1b,
    const float* __restrict__ c2w, const float* __restrict__ c2b,
    const float* __restrict__ s1w, const float* __restrict__ s2w,
    const float* __restrict__ s2b, const float* __restrict__ s3w,
    const float* __restrict__ s3b, const float* __restrict__ ws_s1bp,
    float* __restrict__ out)
{
  __shared__ union { SW1 w1; SW2 w2; } S;
  __shared__ int   s_cards[64];
  __shared__ float s_invlen[TB];
  __shared__ float s_gs[TB][12];
  __shared__ float s_s1bp[20][65];

  const int t = threadIdx.x;
  const int base = blockIdx.x * TB;
  const int lw = t & 63, wv = t >> 6;
  const int e8 = lw >> 3, kc = lw & 7;

  // ---- P0a ----
  if (t < 64) s_cards[t] = hand_cards[base * 8 + t];
  if (t < TB) { int hs = hand_size[base + t]; s_invlen[t] = 1.0f / (float)(hs > 1 ? hs : 1); }
  if (t >= 64 && t < 64 + TB * 12) {
    int i = t - 64; s_gs[i / 12][i % 12] = game_state[(base + i / 12) * 12 + i % 12];
  }
  for (int o = t; o < 20 * 64; o += NT) s_s1bp[o >> 6][o & 63] = ws_s1bp[o];
  __syncthreads();

  // ---- P0b: gather x = emb[cards] -> bf16 LDS ----
  {
    int es = t >> 2, k0 = (t & 3) * 16;
    const float* src = emb + s_cards[es] * 64 + k0;
    float4 v0 = *(const float4*)(src);
    float4 v1 = *(const float4*)(src + 4);
    float4 v2 = *(const float4*)(src + 8);
    float4 v3 = *(const float4*)(src + 12);
    uint4 pa = make_uint4(pk2(v0.x,v0.y), pk2(v0.z,v0.w), pk2(v1.x,v1.y), pk2(v1.z,v1.w));
    uint4 pb = make_uint4(pk2(v2.x,v2.y), pk2(v2.z,v2.w), pk2(v3.x,v3.y), pk2(v3.z,v3.w));
    *(uint4*)(S.w1.x_ah + es * 72 + k0) = pa;
    *(uint4*)(S.w1.x_ah + es * 72 + k0 + 8) = pb;
  }
  __syncthreads();

  // ---- P1: qkv = x @ ipw.T + ipb  (k-split: lane pair = (row, k-half); 32 regs) ----
  {
    const int row = (wv & 1) * 32 + (lw >> 1);   // 0..63
    const int kh  = (lw & 1) * 32;               // k offset: 0 or 32
    const int f0  = (wv >> 1) * 96;              // f range start: 0 or 96
    float xr[32];
    {
      const u16* xrow = S.w1.x_ah + row * 72 + kh;
#pragma unroll
      for (int k8 = 0; k8 < 4; ++k8) {
        uint4 u = *(const uint4*)(xrow + k8 * 8);
        float2 f01 = up2(u.x), f23 = up2(u.y), f45 = up2(u.z), f67 = up2(u.w);
        xr[k8*8+0]=f01.x; xr[k8*8+1]=f01.y; xr[k8*8+2]=f23.x; xr[k8*8+3]=f23.y;
        xr[k8*8+4]=f45.x; xr[k8*8+5]=f45.y; xr[k8*8+6]=f67.x; xr[k8*8+7]=f67.y;
      }
    }
    for (int fi = 0; fi < 96; ++fi) {
      const int f = f0 + fi;
      const float* wr = ipw + f * 64 + kh;
      float a0 = 0.f, a1 = 0.f, a2 = 0.f, a3 = 0.f;
#pragma unroll
      for (int k = 0; k < 32; k += 4) {
        float4 w4 = *(const float4*)(wr + k);
        a0 += xr[k] * w4.x;   a1 += xr[k+1] * w4.y;
        a2 += xr[k+2] * w4.z; a3 += xr[k+3] * w4.w;
      }
      float a = (a0 + a1) + (a2 + a3);
      a += __shfl_xor(a, 1);
      if ((lw & 1) == 0) S.w1.qkv[row * 200 + f] = f2bf(a + ipb[f]);
    }
  }
  __syncthreads();

  // ---- P2: masked scaled scores + softmax ----
  {
    int e = t >> 5, h = (t >> 3) & 3, q = t & 7;
    const u16* qrow = S.w1.qkv + (e * 8 + q) * 200 + h * 16;
    float qr[16];
    up8(*(const uint4*)(qrow), qr);
    up8(*(const uint4*)(qrow + 8), qr + 8);
    float sc[8];
#pragma unroll
    for (int kk = 0; kk < 8; ++kk) {
      const u16* krow = S.w1.qkv + (e * 8 + kk) * 200 + 64 + h * 16;
      float kr[16];
      up8(*(const uint4*)(krow), kr);
      up8(*(const uint4*)(krow + 8), kr + 8);
      float a0 = 0.f;
#pragma unroll
      for (int d = 0; d < 16; ++d) a0 += qr[d] * kr[d];
      sc[kk] = (s_cards[e * 8 + kk] != 0) ? a0 * 0.25f : -1e9f;
    }
    float m = sc[0];
#pragma unroll
    for (int kk = 1; kk < 8; ++kk) m = fmaxf(m, sc[kk]);
    float ssum = 0.f;
#pragma unroll
    for (int kk = 0; kk < 8; ++kk) { sc[kk] = __expf(sc[kk] - m); ssum += sc[kk]; }
    float inv = 1.f / ssum;
    float* dst = S.w1.sc + ((e * 4 + h) * 8 + q) * 9;
#pragma unroll
    for (int kk = 0; kk < 8; ++kk) dst[kk] = sc[kk] * inv;
  }
  __syncthreads();

  // ---- P4: ah = attn @ V -> bf16 into x_ah overlay ----
  {
    int es = lw, h = wv;
    int e = es >> 3, q = es & 7;
    const float* pr = S.w1.sc + ((e * 4 + h) * 8 + q) * 9;
    float p[8];
#pragma unroll
    for (int kk = 0; kk < 8; ++kk) p[kk] = pr[kk];
    float acc[16];
#pragma unroll
    for (int d = 0; d < 16; ++d) acc[d] = 0.f;
#pragma unroll
    for (int kk = 0; kk < 8; ++kk) {
      const u16* vrow = S.w1.qkv + (e * 8 + kk) * 200 + 128 + h * 16;
      float vv[16];
      up8(*(const uint4*)(vrow), vv);
      up8(*(const uint4*)(vrow + 8), vv + 8);
#pragma unroll
      for (int d = 0; d < 16; ++d) acc[d] += p[kk] * vv[d];
    }
    uint4 oa = make_uint4(pk2(acc[0],acc[1]), pk2(acc[2],acc[3]), pk2(acc[4],acc[5]), pk2(acc[6],acc[7]));
    uint4 oc = make_uint4(pk2(acc[8],acc[9]), pk2(acc[10],acc[11]), pk2(acc[12],acc[13]), pk2(acc[14],acc[15]));
    *(uint4*)(S.w1.x_ah + es * 72 + h * 16) = oa;
    *(uint4*)(S.w1.x_ah + es * 72 + h * 16 + 8) = oc;
  }
  __syncthreads();

  // ---- P5a: hx = sum_q ah ; g1 MLP ; stage w2t ----
  for (int o = t; o < TB * 64; o += NT) {
    int e = o >> 6, k = o & 63;
    float s = 0.f;
#pragma unroll
    for (int q = 0; q < 8; ++q) s += bf2f(S.w2.x_ah[(e * 8 + q) * 72 + k]);
    S.w2.hx[e][k] = s;
  }
  for (int o = t; o < TB * 64; o += NT) {
    int e = o >> 6, f = o & 63;
    float acc = g1b[f];
#pragma unroll
    for (int k = 0; k < 12; ++k) acc += s_gs[e][k] * g1w[f * 12 + k];
    S.w2.g1[e][f] = fmaxf(acc, 0.f);
  }
  for (int o = t; o < 2048; o += NT) {
    int m = o >> 6, j = o & 63;
    S.w2.w2t[j][m] = s2w[o];
  }
  __syncthreads();

  // ---- P5b: hand_ctx (8e x 8kc split dot) ; g2 MLP ----
  for (int f = wv; f < 64; f += 4) {
    const float* wr = ow + f * 64 + kc;
    const float* hr = &S.w2.hx[e8][kc];
    float p = 0.f;
#pragma unroll
    for (int j = 0; j < 8; ++j) p += hr[8 * j] * wr[8 * j];
    p += __shfl_xor(p, 1); p += __shfl_xor(p, 2); p += __shfl_xor(p, 4);
    if (kc == 0) S.w2.hand[e8][f] = (p + 8.f * ob[f]) * s_invlen[e8];
  }
  for (int f = wv; f < 32; f += 4) {
    const float* wr = g2w + f * 64 + kc;
    const float* gr = &S.w2.g1[e8][kc];
    float p = 0.f;
#pragma unroll
    for (int j = 0; j < 8; ++j) p += gr[8 * j] * wr[8 * j];
    p += __shfl_xor(p, 1); p += __shfl_xor(p, 2); p += __shfl_xor(p, 4);
    if (kc == 0) S.w2.g[e8][f] = fmaxf(p + g2b[f], 0.f);
  }
  __syncthreads();

  // ---- P6: ctx = relu(c1 @ concat(hand, g)) ----
  for (int f = wv; f < 128; f += 4) {
    const float* wr = c1w + f * 96;
    const float* hr = &S.w2.hand[e8][kc];
    const float* gr = &S.w2.g[e8][kc];
    float p = 0.f;
#pragma unroll
    for (int j = 0; j < 8; ++j) p += hr[8 * j] * wr[kc + 8 * j];
#pragma unroll
    for (int j = 0; j < 4; ++j) p += gr[8 * j] * wr[64 + kc + 8 * j];
    p += __shfl_xor(p, 1); p += __shfl_xor(p, 2); p += __shfl_xor(p, 4);
    if (kc == 0) S.w2.ctx[e8][f] = fmaxf(p + c1b[f], 0.f);
  }
  __syncthreads();

  // ---- P7: ctx2 = relu(c2 @ ctx) ----
  for (int f = wv; f < 128; f += 4) {
    const float* wr = c2w + f * 128 + kc;
    const float* xr2 = &S.w2.ctx[e8][kc];
    float p = 0.f;
#pragma unroll
    for (int j = 0; j < 16; ++j) p += xr2[8 * j] * wr[8 * j];
    p += __shfl_xor(p, 1); p += __shfl_xor(p, 2); p += __shfl_xor(p, 4);
    if (kc == 0) S.w2.ctx2[e8][f] = fmaxf(p + c2b[f], 0.f);
  }
  __syncthreads();

  // ---- P8: s1a = ctx2 @ s1w[:,:128].T (bias lives in s1bp) ----
  for (int f = wv; f < 64; f += 4) {
    const float* wr = s1w + f * 192 + kc;
    const float* xr2 = &S.w2.ctx2[e8][kc];
    float p = 0.f;
#pragma unroll
    for (int j = 0; j < 16; ++j) p += xr2[8 * j] * wr[8 * j];
    p += __shfl_xor(p, 1); p += __shfl_xor(p, 2); p += __shfl_xor(p, 4);
    if (kc == 0) S.w2.s1a[e8][f] = p;
  }
  __syncthreads();

  // ---- P9: per-(e,a) scorer ----
  if (t < TB * 20) {
    int e = t / 20, a = t - e * 20;
    int nv = num_valid[0];
    float acc[32];
#pragma unroll
    for (int m = 0; m < 32; ++m) acc[m] = s2b[m];
    for (int j = 0; j < 64; ++j) {
      float hj = fmaxf(S.w2.s1a[e][j] + s_s1bp[a][j], 0.f);
      const float* wrow = &S.w2.w2t[j][0];
#pragma unroll
      for (int m4 = 0; m4 < 32; m4 += 4) {
        float4 w4 = *(const float4*)(wrow + m4);
        acc[m4]   += hj * w4.x; acc[m4+1] += hj * w4.y;
        acc[m4+2] += hj * w4.z; acc[m4+3] += hj * w4.w;
      }
    }
    float sc2 = s3b[0];
#pragma unroll
    for (int m = 0; m < 32; ++m) sc2 += fmaxf(acc[m], 0.f) * s3w[m];
    out[base * 20 + t] = (a < nv) ? sc2 : -1e8f;
  }
}

extern "C" void kernel_launch(void* const* d_in, const int* in_sizes, int n_in,
                              void* d_out, int out_size, void* d_ws, size_t ws_size,
                              hipStream_t stream) {
  (void)in_sizes; (void)n_in; (void)out_size; (void)ws_size;
  float* out = (float*)d_out;
  float* ws = (float*)d_ws;

  hipLaunchKernelGGL(prep_kernel, dim3(1), dim3(256), 0, stream,
                     (const float*)d_in[6], (const int*)d_in[3], (const int*)d_in[4],
                     (const float*)d_in[19], (const float*)d_in[20], ws);
  hipLaunchKernelGGL(policy_fused, dim3(32768 / TB), dim3(NT), 0, stream,
                     (const int*)d_in[0],  (const float*)d_in[1], (const int*)d_in[2],
                     (const int*)d_in[5],
                     (const float*)d_in[6],  (const float*)d_in[7],  (const float*)d_in[8],
                     (const float*)d_in[9],  (const float*)d_in[10],
                     (const float*)d_in[11], (const float*)d_in[12],
                     (const float*)d_in[13], (const float*)d_in[14],
                     (const float*)d_in[15], (const float*)d_in[16],
                     (const float*)d_in[17], (const float*)d_in[18],
                     (const float*)d_in[19], (const float*)d_in[21],
                     (const float*)d_in[22], (const float*)d_in[23],
                     (const float*)d_in[24], ws, out);
}

// Round 5
// 314.334 us; speedup vs baseline: 3.1755x; 3.1755x over previous
//
#include <hip/hip_runtime.h>
#include <hip/hip_bf16.h>

#define NT 256
#define TB 8   // batch elements per block

typedef unsigned short u16;
typedef unsigned int u32;
typedef __attribute__((ext_vector_type(8))) short short8v;  // 8 bf16 (4 VGPRs)
typedef __attribute__((ext_vector_type(4))) float f32x4;

__device__ __forceinline__ float bf2f(u16 u) {
  union { u32 i; float f; } v; v.i = ((u32)u) << 16; return v.f;
}
__device__ __forceinline__ float2 up2(u32 p) {
  union { u32 i; float f; } a, b;
  a.i = p << 16; b.i = p & 0xffff0000u;
  return make_float2(a.f, b.f);
}
__device__ __forceinline__ u16 f2bf(float f) {
  union { float f; u32 i; } v; v.f = f;
  u32 r = v.i + 0x7fffu + ((v.i >> 16) & 1u);  // round-to-nearest-even
  return (u16)(r >> 16);
}
__device__ __forceinline__ u32 pk2(float a, float b) {
  return (u32)f2bf(a) | ((u32)f2bf(b) << 16);
}
__device__ __forceinline__ void up8(uint4 u, float* d) {
  float2 f;
  f = up2(u.x); d[0]=f.x; d[1]=f.y;
  f = up2(u.y); d[2]=f.x; d[3]=f.y;
  f = up2(u.z); d[4]=f.x; d[5]=f.y;
  f = up2(u.w); d[6]=f.x; d[7]=f.y;
}

// prep: s1bp[a][f] = s1_b + arep @ s1w[:,128:].T -> ws[0..1279] (f32)
//       ipw converted to bf16 [192][64]          -> ws+1280 (u16)
__global__ void prep_kernel(const float* __restrict__ emb, const int* __restrict__ act_idx,
                            const int* __restrict__ act_cnt, const float* __restrict__ s1w,
                            const float* __restrict__ s1b, const float* __restrict__ ipw,
                            float* __restrict__ ws) {
  __shared__ float s_arep[20][64];
  int t = threadIdx.x;
  for (int o = t; o < 20 * 64; o += 256) {
    int a = o >> 6, k = o & 63;
    int cnt = act_cnt[a];
    float sum = 0.f;
#pragma unroll
    for (int j = 0; j < 4; ++j)
      if (j < cnt) sum += emb[act_idx[a * 4 + j] * 64 + k];
    s_arep[a][k] = sum / (float)(cnt > 1 ? cnt : 1);
  }
  __syncthreads();
  for (int o = t; o < 20 * 64; o += 256) {
    int a = o >> 6, f = o & 63;
    const float* wr = s1w + f * 192 + 128;
    float acc = s1b[f];
#pragma unroll 8
    for (int k = 0; k < 64; ++k) acc += s_arep[a][k] * wr[k];
    ws[o] = acc;
  }
  u16* wbf = (u16*)(ws + 1280);
  for (int o = t; o < 192 * 64; o += 256) wbf[o] = f2bf(ipw[o]);
}

// LDS map (bytes), total 35488:
//   region A [0..25600):   x[64][72] u16 (P0b-P1A) -> qkv[64][200] u16 (P1-P4)
//                          -> SW2 floats: hx@0 g1@2176 hand@4352 g@6528
//                             ctx@7680 ctx2@11904 s1a@16128 (P5a-P9)
//   region B [25600..34816): sc[2304] f32 pad9 (P2-P4) -> ah[64][72] u16 (P4-P5a)
//                          -> w2t[64][36] f32 (P5b-P9)
//   extras: cards@34816 invlen@35072 gs@35104
__global__ __launch_bounds__(NT, 4) void policy_fused(
    const int* __restrict__ hand_cards, const float* __restrict__ game_state,
    const int* __restrict__ hand_size, const int* __restrict__ num_valid,
    const float* __restrict__ emb, const float* __restrict__ ipb,
    const float* __restrict__ ow, const float* __restrict__ ob,
    const float* __restrict__ g1w, const float* __restrict__ g1b,
    const float* __restrict__ g2w, const float* __restrict__ g2b,
    const float* __restrict__ c1w, const float* __restrict__ c1b,
    const float* __restrict__ c2w, const float* __restrict__ c2b,
    const float* __restrict__ s1w, const float* __restrict__ s2w,
    const float* __restrict__ s2b, const float* __restrict__ s3w,
    const float* __restrict__ s3b, const float* __restrict__ ws,
    float* __restrict__ out)
{
  __shared__ __align__(16) unsigned char s_raw[35488];
  u16*   s_x    = (u16*)s_raw;                 // [64][72]
  u16*   s_qkv  = (u16*)s_raw;                 // [64][200]
  float* s_sc   = (float*)(s_raw + 25600);     // [2304] pad 9
  u16*   s_ah   = (u16*)(s_raw + 25600);       // [64][72]
  float* s_w2t  = (float*)(s_raw + 25600);     // [64][36]
  float* s_hx   = (float*)(s_raw + 0);         // [8][68]
  float* s_g1   = (float*)(s_raw + 2176);      // [8][68]
  float* s_hand = (float*)(s_raw + 4352);      // [8][68]
  float* s_g    = (float*)(s_raw + 6528);      // [8][36]
  float* s_ctx  = (float*)(s_raw + 7680);      // [8][132]
  float* s_ctx2 = (float*)(s_raw + 11904);     // [8][132]
  float* s_s1a  = (float*)(s_raw + 16128);     // [8][68]
  int*   s_cards  = (int*)(s_raw + 34816);     // [64]
  float* s_invlen = (float*)(s_raw + 35072);   // [8]
  float* s_gs   = (float*)(s_raw + 35104);     // [8][12]

  const float* ws_s1bp = ws;                   // [20][64]
  const u16*   wqkv    = (const u16*)(ws + 1280);  // bf16 ipw [192][64]

  const int t = threadIdx.x;
  const int base = blockIdx.x * TB;
  const int lw = t & 63, wv = t >> 6;
  const int e8 = lw >> 3, kc = lw & 7;

  // ---- P0a ----
  if (t < 64) s_cards[t] = hand_cards[base * 8 + t];
  if (t < TB) { int hs = hand_size[base + t]; s_invlen[t] = 1.0f / (float)(hs > 1 ? hs : 1); }
  if (t >= 64 && t < 64 + TB * 12) {
    int i = t - 64; s_gs[(i / 12) * 12 + (i % 12)] = game_state[(base + i / 12) * 12 + i % 12];
  }
  __syncthreads();

  // ---- P0b: gather x = emb[cards] -> bf16 LDS ----
  {
    int es = t >> 2, k0 = (t & 3) * 16;
    const float* src = emb + s_cards[es] * 64 + k0;
    float4 v0 = *(const float4*)(src);
    float4 v1 = *(const float4*)(src + 4);
    float4 v2 = *(const float4*)(src + 8);
    float4 v3 = *(const float4*)(src + 12);
    uint4 pa = make_uint4(pk2(v0.x,v0.y), pk2(v0.z,v0.w), pk2(v1.x,v1.y), pk2(v1.z,v1.w));
    uint4 pb = make_uint4(pk2(v2.x,v2.y), pk2(v2.z,v2.w), pk2(v3.x,v3.y), pk2(v3.z,v3.w));
    *(uint4*)(s_x + es * 72 + k0) = pa;
    *(uint4*)(s_x + es * 72 + k0 + 8) = pb;
  }
  __syncthreads();

  // ---- P1: qkv = x @ ipw.T + ipb via MFMA 16x16x32_bf16 ----
  // wave wv owns tokens wv*16..wv*16+15; A frag: lane row=lw&15, k=(lw>>4)*8+j
  {
    const int kq = lw >> 4, rr = lw & 15;
    const int tok = wv * 16 + rr;
    short8v a0 = *(const short8v*)(s_x + tok * 72 + kq * 8);        // k 0..31
    short8v a1 = *(const short8v*)(s_x + tok * 72 + 32 + kq * 8);   // k 32..63
    __syncthreads();   // all A frags in regs; qkv may now overwrite x
    const int trow = wv * 16 + kq * 4;
    for (int n = 0; n < 12; ++n) {
      const int f = n * 16 + rr;                                     // C col = lane&15
      short8v b0 = *(const short8v*)(wqkv + f * 64 + kq * 8);
      short8v b1 = *(const short8v*)(wqkv + f * 64 + 32 + kq * 8);
      float bias = ipb[f];
      f32x4 acc = { bias, bias, bias, bias };
      acc = __builtin_amdgcn_mfma_f32_16x16x32_bf16(a0, b0, acc, 0, 0, 0);
      acc = __builtin_amdgcn_mfma_f32_16x16x32_bf16(a1, b1, acc, 0, 0, 0);
#pragma unroll
      for (int r = 0; r < 4; ++r)                                    // C row=(l>>4)*4+r
        s_qkv[(trow + r) * 200 + f] = f2bf(acc[r]);
    }
  }
  __syncthreads();

  // ---- P2: masked scaled scores + softmax ----
  {
    int e = t >> 5, h = (t >> 3) & 3, q = t & 7;
    const u16* qrow = s_qkv + (e * 8 + q) * 200 + h * 16;
    float qr[16];
    up8(*(const uint4*)(qrow), qr);
    up8(*(const uint4*)(qrow + 8), qr + 8);
    float sc[8];
#pragma unroll
    for (int kk = 0; kk < 8; ++kk) {
      const u16* krow = s_qkv + (e * 8 + kk) * 200 + 64 + h * 16;
      float kr[16];
      up8(*(const uint4*)(krow), kr);
      up8(*(const uint4*)(krow + 8), kr + 8);
      float a0 = 0.f;
#pragma unroll
      for (int d = 0; d < 16; ++d) a0 += qr[d] * kr[d];
      sc[kk] = (s_cards[e * 8 + kk] != 0) ? a0 * 0.25f : -1e9f;
    }
    float m = sc[0];
#pragma unroll
    for (int kk = 1; kk < 8; ++kk) m = fmaxf(m, sc[kk]);
    float ssum = 0.f;
#pragma unroll
    for (int kk = 0; kk < 8; ++kk) { sc[kk] = __expf(sc[kk] - m); ssum += sc[kk]; }
    float inv = 1.f / ssum;
    float* dst = s_sc + ((e * 4 + h) * 8 + q) * 9;
#pragma unroll
    for (int kk = 0; kk < 8; ++kk) dst[kk] = sc[kk] * inv;
  }
  __syncthreads();

  // ---- P4: ah = attn @ V ; ah overlays sc (probs -> regs, barrier, write) ----
  {
    int es = lw, h = wv;
    int e = es >> 3, q = es & 7;
    const float* pr = s_sc + ((e * 4 + h) * 8 + q) * 9;
    float p[8];
#pragma unroll
    for (int kk = 0; kk < 8; ++kk) p[kk] = pr[kk];
    __syncthreads();   // all prob reads done before ah overwrites sc
    float acc[16];
#pragma unroll
    for (int d = 0; d < 16; ++d) acc[d] = 0.f;
#pragma unroll
    for (int kk = 0; kk < 8; ++kk) {
      const u16* vrow = s_qkv + (e * 8 + kk) * 200 + 128 + h * 16;
      float vv[16];
      up8(*(const uint4*)(vrow), vv);
      up8(*(const uint4*)(vrow + 8), vv + 8);
#pragma unroll
      for (int d = 0; d < 16; ++d) acc[d] += p[kk] * vv[d];
    }
    uint4 oa = make_uint4(pk2(acc[0],acc[1]), pk2(acc[2],acc[3]), pk2(acc[4],acc[5]), pk2(acc[6],acc[7]));
    uint4 oc = make_uint4(pk2(acc[8],acc[9]), pk2(acc[10],acc[11]), pk2(acc[12],acc[13]), pk2(acc[14],acc[15]));
    *(uint4*)(s_ah + es * 72 + h * 16) = oa;
    *(uint4*)(s_ah + es * 72 + h * 16 + 8) = oc;
  }
  __syncthreads();

  // ---- P5a: hx = sum_q ah (into dead qkv region) ; g1 MLP ----
  for (int o = t; o < TB * 64; o += NT) {
    int e = o >> 6, k = o & 63;
    float s = 0.f;
#pragma unroll
    for (int q = 0; q < 8; ++q) s += bf2f(s_ah[(e * 8 + q) * 72 + k]);
    s_hx[e * 68 + k] = s;
  }
  for (int o = t; o < TB * 64; o += NT) {
    int e = o >> 6, f = o & 63;
    float acc = g1b[f];
#pragma unroll
    for (int k = 0; k < 12; ++k) acc += s_gs[e * 12 + k] * g1w[f * 12 + k];
    s_g1[e * 68 + f] = fmaxf(acc, 0.f);
  }
  __syncthreads();

  // ---- P5b: stage w2t (over dead ah) ; hand_ctx ; g2 MLP ----
  for (int o = t; o < 2048; o += NT) {
    int m = o >> 6, j = o & 63;
    s_w2t[j * 36 + m] = s2w[o];
  }
  for (int f = wv; f < 64; f += 4) {
    const float* wr = ow + f * 64 + kc;
    const float* hr = s_hx + e8 * 68 + kc;
    float p = 0.f;
#pragma unroll
    for (int j = 0; j < 8; ++j) p += hr[8 * j] * wr[8 * j];
    p += __shfl_xor(p, 1); p += __shfl_xor(p, 2); p += __shfl_xor(p, 4);
    if (kc == 0) s_hand[e8 * 68 + f] = (p + 8.f * ob[f]) * s_invlen[e8];
  }
  for (int f = wv; f < 32; f += 4) {
    const float* wr = g2w + f * 64 + kc;
    const float* gr = s_g1 + e8 * 68 + kc;
    float p = 0.f;
#pragma unroll
    for (int j = 0; j < 8; ++j) p += gr[8 * j] * wr[8 * j];
    p += __shfl_xor(p, 1); p += __shfl_xor(p, 2); p += __shfl_xor(p, 4);
    if (kc == 0) s_g[e8 * 36 + f] = fmaxf(p + g2b[f], 0.f);
  }
  __syncthreads();

  // ---- P6: ctx = relu(c1 @ concat(hand, g)) ----
  for (int f = wv; f < 128; f += 4) {
    const float* wr = c1w + f * 96;
    const float* hr = s_hand + e8 * 68 + kc;
    const float* gr = s_g + e8 * 36 + kc;
    float p = 0.f;
#pragma unroll
    for (int j = 0; j < 8; ++j) p += hr[8 * j] * wr[kc + 8 * j];
#pragma unroll
    for (int j = 0; j < 4; ++j) p += gr[8 * j] * wr[64 + kc + 8 * j];
    p += __shfl_xor(p, 1); p += __shfl_xor(p, 2); p += __shfl_xor(p, 4);
    if (kc == 0) s_ctx[e8 * 132 + f] = fmaxf(p + c1b[f], 0.f);
  }
  __syncthreads();

  // ---- P7: ctx2 = relu(c2 @ ctx) ----
  for (int f = wv; f < 128; f += 4) {
    const float* wr = c2w + f * 128 + kc;
    const float* xr2 = s_ctx + e8 * 132 + kc;
    float p = 0.f;
#pragma unroll
    for (int j = 0; j < 16; ++j) p += xr2[8 * j] * wr[8 * j];
    p += __shfl_xor(p, 1); p += __shfl_xor(p, 2); p += __shfl_xor(p, 4);
    if (kc == 0) s_ctx2[e8 * 132 + f] = fmaxf(p + c2b[f], 0.f);
  }
  __syncthreads();

  // ---- P8: s1a = ctx2 @ s1w[:,:128].T ----
  for (int f = wv; f < 64; f += 4) {
    const float* wr = s1w + f * 192 + kc;
    const float* xr2 = s_ctx2 + e8 * 132 + kc;
    float p = 0.f;
#pragma unroll
    for (int j = 0; j < 16; ++j) p += xr2[8 * j] * wr[8 * j];
    p += __shfl_xor(p, 1); p += __shfl_xor(p, 2); p += __shfl_xor(p, 4);
    if (kc == 0) s_s1a[e8 * 68 + f] = p;
  }
  __syncthreads();

  // ---- P9: per-(e,a) scorer; s1bp from L1-resident global ----
  if (t < TB * 20) {
    int e = t / 20, a = t - e * 20;
    int nv = num_valid[0];
    const float* bp = ws_s1bp + a * 64;
    float acc[32];
#pragma unroll
    for (int m = 0; m < 32; ++m) acc[m] = s2b[m];
    for (int j = 0; j < 64; ++j) {
      float hj = fmaxf(s_s1a[e * 68 + j] + bp[j], 0.f);
      const float* wrow = s_w2t + j * 36;
#pragma unroll
      for (int m4 = 0; m4 < 32; m4 += 4) {
        float4 w4 = *(const float4*)(wrow + m4);
        acc[m4]   += hj * w4.x; acc[m4+1] += hj * w4.y;
        acc[m4+2] += hj * w4.z; acc[m4+3] += hj * w4.w;
      }
    }
    float sc2 = s3b[0];
#pragma unroll
    for (int m = 0; m < 32; ++m) sc2 += fmaxf(acc[m], 0.f) * s3w[m];
    out[base * 20 + t] = (a < nv) ? sc2 : -1e8f;
  }
}

extern "C" void kernel_launch(void* const* d_in, const int* in_sizes, int n_in,
                              void* d_out, int out_size, void* d_ws, size_t ws_size,
                              hipStream_t stream) {
  (void)in_sizes; (void)n_in; (void)out_size; (void)ws_size;
  float* out = (float*)d_out;
  float* ws = (float*)d_ws;

  hipLaunchKernelGGL(prep_kernel, dim3(1), dim3(256), 0, stream,
                     (const float*)d_in[6], (const int*)d_in[3], (const int*)d_in[4],
                     (const float*)d_in[19], (const float*)d_in[20],
                     (const float*)d_in[7], ws);
  hipLaunchKernelGGL(policy_fused, dim3(32768 / TB), dim3(NT), 0, stream,
                     (const int*)d_in[0],  (const float*)d_in[1], (const int*)d_in[2],
                     (const int*)d_in[5],
                     (const float*)d_in[6],  (const float*)d_in[8],
                     (const float*)d_in[9],  (const float*)d_in[10],
                     (const float*)d_in[11], (const float*)d_in[12],
                     (const float*)d_in[13], (const float*)d_in[14],
                     (const float*)d_in[15], (const float*)d_in[16],
                     (const float*)d_in[17], (const float*)d_in[18],
                     (const float*)d_in[19], (const float*)d_in[21],
                     (const float*)d_in[22], (const float*)d_in[23],
                     (const float*)d_in[24], ws, out);
}

// Round 6
// 298.881 us; speedup vs baseline: 3.3397x; 1.0517x over previous
//
#include <hip/hip_runtime.h>
#include <hip/hip_bf16.h>

#define NT 256
#define TB 8   // batch elements per block

typedef unsigned short u16;
typedef unsigned int u32;
typedef __attribute__((ext_vector_type(8))) short short8v;  // 8 bf16 (4 VGPRs)
typedef __attribute__((ext_vector_type(4))) float f32x4;

__device__ __forceinline__ float bf2f(u16 u) {
  union { u32 i; float f; } v; v.i = ((u32)u) << 16; return v.f;
}
__device__ __forceinline__ float2 up2(u32 p) {
  union { u32 i; float f; } a, b;
  a.i = p << 16; b.i = p & 0xffff0000u;
  return make_float2(a.f, b.f);
}
__device__ __forceinline__ u16 f2bf(float f) {
  union { float f; u32 i; } v; v.f = f;
  u32 r = v.i + 0x7fffu + ((v.i >> 16) & 1u);  // round-to-nearest-even
  return (u16)(r >> 16);
}
__device__ __forceinline__ u32 pk2(float a, float b) {
  return (u32)f2bf(a) | ((u32)f2bf(b) << 16);
}
__device__ __forceinline__ void up8(uint4 u, float* d) {
  float2 f;
  f = up2(u.x); d[0]=f.x; d[1]=f.y;
  f = up2(u.y); d[2]=f.x; d[3]=f.y;
  f = up2(u.z); d[4]=f.x; d[5]=f.y;
  f = up2(u.w); d[6]=f.x; d[7]=f.y;
}

// prep: s1bp[a][f] = s1_b + arep @ s1w[:,128:].T -> ws[0..1279] (f32)
//       ipw -> bf16 [192][64] at ws+1280 ; s2w -> bf16 [32][64] after it
__global__ void prep_kernel(const float* __restrict__ emb, const int* __restrict__ act_idx,
                            const int* __restrict__ act_cnt, const float* __restrict__ s1w,
                            const float* __restrict__ s1b, const float* __restrict__ ipw,
                            const float* __restrict__ s2w, float* __restrict__ ws) {
  __shared__ float s_arep[20][64];
  int t = threadIdx.x;
  for (int o = t; o < 20 * 64; o += 256) {
    int a = o >> 6, k = o & 63;
    int cnt = act_cnt[a];
    float sum = 0.f;
#pragma unroll
    for (int j = 0; j < 4; ++j)
      if (j < cnt) sum += emb[act_idx[a * 4 + j] * 64 + k];
    s_arep[a][k] = sum / (float)(cnt > 1 ? cnt : 1);
  }
  __syncthreads();
  for (int o = t; o < 20 * 64; o += 256) {
    int a = o >> 6, f = o & 63;
    const float* wr = s1w + f * 192 + 128;
    float acc = s1b[f];
#pragma unroll 8
    for (int k = 0; k < 64; ++k) acc += s_arep[a][k] * wr[k];
    ws[o] = acc;
  }
  u16* wbf = (u16*)(ws + 1280);
  for (int o = t; o < 192 * 64; o += 256) wbf[o] = f2bf(ipw[o]);
  u16* wbf2 = wbf + 192 * 64;
  for (int o = t; o < 32 * 64; o += 256) wbf2[o] = f2bf(s2w[o]);
}

// LDS map (bytes), total 35488:
//   region A [0..25600): x[64][72] u16 -> qkv[64][200] u16 ->
//     floats hx@0 g1@2176 hand@4352 g@6528 ctx@7680 ctx2@11904 | s1a@23424
//     then hbf[160][66] u16 @0..21120 (P9a-P9b, over dead hx..ctx2)
//   region B [25600..34816): sc[2304] f32 pad9 -> ah[64][72] u16
//   extras: cards@34816 invlen@35072 gs@35104
__global__ __launch_bounds__(NT, 4) void policy_fused(
    const int* __restrict__ hand_cards, const float* __restrict__ game_state,
    const int* __restrict__ hand_size, const int* __restrict__ num_valid,
    const float* __restrict__ emb, const float* __restrict__ ipb,
    const float* __restrict__ ow, const float* __restrict__ ob,
    const float* __restrict__ g1w, const float* __restrict__ g1b,
    const float* __restrict__ g2w, const float* __restrict__ g2b,
    const float* __restrict__ c1w, const float* __restrict__ c1b,
    const float* __restrict__ c2w, const float* __restrict__ c2b,
    const float* __restrict__ s1w, const float* __restrict__ s2b,
    const float* __restrict__ s3w, const float* __restrict__ s3b,
    const float* __restrict__ ws, float* __restrict__ out)
{
  __shared__ __align__(16) unsigned char s_raw[35488];
  u16*   s_x    = (u16*)s_raw;                 // [64][72]
  u16*   s_qkv  = (u16*)s_raw;                 // [64][200]
  float* s_sc   = (float*)(s_raw + 25600);     // [2304] pad 9
  u16*   s_ah   = (u16*)(s_raw + 25600);       // [64][72]
  float* s_hx   = (float*)(s_raw + 0);         // [8][68]
  float* s_g1   = (float*)(s_raw + 2176);      // [8][68]
  float* s_hand = (float*)(s_raw + 4352);      // [8][68]
  float* s_g    = (float*)(s_raw + 6528);      // [8][36]
  float* s_ctx  = (float*)(s_raw + 7680);      // [8][132]
  float* s_ctx2 = (float*)(s_raw + 11904);     // [8][132]
  u16*   s_hbf  = (u16*)s_raw;                 // [160][66] (P9, over dead scratch)
  float* s_s1a  = (float*)(s_raw + 23424);     // [8][68]
  int*   s_cards  = (int*)(s_raw + 34816);     // [64]
  float* s_invlen = (float*)(s_raw + 35072);   // [8]
  float* s_gs   = (float*)(s_raw + 35104);     // [8][12]

  const float* ws_s1bp = ws;                        // [20][64]
  const u16*   wqkv    = (const u16*)(ws + 1280);   // bf16 ipw [192][64]
  const u16*   s2wbf   = wqkv + 192 * 64;           // bf16 s2w [32][64]

  const int t = threadIdx.x;
  const int base = blockIdx.x * TB;
  const int lw = t & 63, wv = t >> 6;
  const int e8 = lw >> 3, kc = lw & 7;

  // ---- P0a ----
  if (t < 64) s_cards[t] = hand_cards[base * 8 + t];
  if (t < TB) { int hs = hand_size[base + t]; s_invlen[t] = 1.0f / (float)(hs > 1 ? hs : 1); }
  if (t >= 64 && t < 64 + TB * 12) {
    int i = t - 64; s_gs[(i / 12) * 12 + (i % 12)] = game_state[(base + i / 12) * 12 + i % 12];
  }
  __syncthreads();

  // ---- P0b: gather x = emb[cards] -> bf16 LDS ----
  {
    int es = t >> 2, k0 = (t & 3) * 16;
    const float* src = emb + s_cards[es] * 64 + k0;
    float4 v0 = *(const float4*)(src);
    float4 v1 = *(const float4*)(src + 4);
    float4 v2 = *(const float4*)(src + 8);
    float4 v3 = *(const float4*)(src + 12);
    uint4 pa = make_uint4(pk2(v0.x,v0.y), pk2(v0.z,v0.w), pk2(v1.x,v1.y), pk2(v1.z,v1.w));
    uint4 pb = make_uint4(pk2(v2.x,v2.y), pk2(v2.z,v2.w), pk2(v3.x,v3.y), pk2(v3.z,v3.w));
    *(uint4*)(s_x + es * 72 + k0) = pa;
    *(uint4*)(s_x + es * 72 + k0 + 8) = pb;
  }
  __syncthreads();

  // ---- P1: qkv = x @ ipw.T + ipb via MFMA 16x16x32_bf16 ----
  {
    const int kq = lw >> 4, rr = lw & 15;
    const int tok = wv * 16 + rr;
    short8v a0 = *(const short8v*)(s_x + tok * 72 + kq * 8);        // k 0..31
    short8v a1 = *(const short8v*)(s_x + tok * 72 + 32 + kq * 8);   // k 32..63
    __syncthreads();   // all A frags in regs; qkv may now overwrite x
    const int trow = wv * 16 + kq * 4;
    for (int n = 0; n < 12; ++n) {
      const int f = n * 16 + rr;                                     // C col = lane&15
      short8v b0 = *(const short8v*)(wqkv + f * 64 + kq * 8);
      short8v b1 = *(const short8v*)(wqkv + f * 64 + 32 + kq * 8);
      float bias = ipb[f];
      f32x4 acc = { bias, bias, bias, bias };
      acc = __builtin_amdgcn_mfma_f32_16x16x32_bf16(a0, b0, acc, 0, 0, 0);
      acc = __builtin_amdgcn_mfma_f32_16x16x32_bf16(a1, b1, acc, 0, 0, 0);
#pragma unroll
      for (int r = 0; r < 4; ++r)                                    // C row=(l>>4)*4+r
        s_qkv[(trow + r) * 200 + f] = f2bf(acc[r]);
    }
  }
  __syncthreads();

  // ---- P2: masked scaled scores + softmax ----
  {
    int e = t >> 5, h = (t >> 3) & 3, q = t & 7;
    const u16* qrow = s_qkv + (e * 8 + q) * 200 + h * 16;
    float qr[16];
    up8(*(const uint4*)(qrow), qr);
    up8(*(const uint4*)(qrow + 8), qr + 8);
    float sc[8];
#pragma unroll
    for (int kk = 0; kk < 8; ++kk) {
      const u16* krow = s_qkv + (e * 8 + kk) * 200 + 64 + h * 16;
      float kr[16];
      up8(*(const uint4*)(krow), kr);
      up8(*(const uint4*)(krow + 8), kr + 8);
      float a0 = 0.f;
#pragma unroll
      for (int d = 0; d < 16; ++d) a0 += qr[d] * kr[d];
      sc[kk] = (s_cards[e * 8 + kk] != 0) ? a0 * 0.25f : -1e9f;
    }
    float m = sc[0];
#pragma unroll
    for (int kk = 1; kk < 8; ++kk) m = fmaxf(m, sc[kk]);
    float ssum = 0.f;
#pragma unroll
    for (int kk = 0; kk < 8; ++kk) { sc[kk] = __expf(sc[kk] - m); ssum += sc[kk]; }
    float inv = 1.f / ssum;
    float* dst = s_sc + ((e * 4 + h) * 8 + q) * 9;
#pragma unroll
    for (int kk = 0; kk < 8; ++kk) dst[kk] = sc[kk] * inv;
  }
  __syncthreads();

  // ---- P4: ah = attn @ V ; ah overlays sc ----
  {
    int es = lw, h = wv;
    int e = es >> 3, q = es & 7;
    const float* pr = s_sc + ((e * 4 + h) * 8 + q) * 9;
    float p[8];
#pragma unroll
    for (int kk = 0; kk < 8; ++kk) p[kk] = pr[kk];
    __syncthreads();   // all prob reads done before ah overwrites sc
    float acc[16];
#pragma unroll
    for (int d = 0; d < 16; ++d) acc[d] = 0.f;
#pragma unroll
    for (int kk = 0; kk < 8; ++kk) {
      const u16* vrow = s_qkv + (e * 8 + kk) * 200 + 128 + h * 16;
      float vv[16];
      up8(*(const uint4*)(vrow), vv);
      up8(*(const uint4*)(vrow + 8), vv + 8);
#pragma unroll
      for (int d = 0; d < 16; ++d) acc[d] += p[kk] * vv[d];
    }
    uint4 oa = make_uint4(pk2(acc[0],acc[1]), pk2(acc[2],acc[3]), pk2(acc[4],acc[5]), pk2(acc[6],acc[7]));
    uint4 oc = make_uint4(pk2(acc[8],acc[9]), pk2(acc[10],acc[11]), pk2(acc[12],acc[13]), pk2(acc[14],acc[15]));
    *(uint4*)(s_ah + es * 72 + h * 16) = oa;
    *(uint4*)(s_ah + es * 72 + h * 16 + 8) = oc;
  }
  __syncthreads();

  // ---- P5a: hx = sum_q ah ; g1 MLP ----
  for (int o = t; o < TB * 64; o += NT) {
    int e = o >> 6, k = o & 63;
    float s = 0.f;
#pragma unroll
    for (int q = 0; q < 8; ++q) s += bf2f(s_ah[(e * 8 + q) * 72 + k]);
    s_hx[e * 68 + k] = s;
  }
  for (int o = t; o < TB * 64; o += NT) {
    int e = o >> 6, f = o & 63;
    float acc = g1b[f];
#pragma unroll
    for (int k = 0; k < 12; ++k) acc += s_gs[e * 12 + k] * g1w[f * 12 + k];
    s_g1[e * 68 + f] = fmaxf(acc, 0.f);
  }
  __syncthreads();

  // ---- P5b: hand_ctx ; g2 MLP ----
  for (int f = wv; f < 64; f += 4) {
    const float* wr = ow + f * 64 + kc;
    const float* hr = s_hx + e8 * 68 + kc;
    float p = 0.f;
#pragma unroll
    for (int j = 0; j < 8; ++j) p += hr[8 * j] * wr[8 * j];
    p += __shfl_xor(p, 1); p += __shfl_xor(p, 2); p += __shfl_xor(p, 4);
    if (kc == 0) s_hand[e8 * 68 + f] = (p + 8.f * ob[f]) * s_invlen[e8];
  }
  for (int f = wv; f < 32; f += 4) {
    const float* wr = g2w + f * 64 + kc;
    const float* gr = s_g1 + e8 * 68 + kc;
    float p = 0.f;
#pragma unroll
    for (int j = 0; j < 8; ++j) p += gr[8 * j] * wr[8 * j];
    p += __shfl_xor(p, 1); p += __shfl_xor(p, 2); p += __shfl_xor(p, 4);
    if (kc == 0) s_g[e8 * 36 + f] = fmaxf(p + g2b[f], 0.f);
  }
  __syncthreads();

  // ---- P6: ctx = relu(c1 @ concat(hand, g)) ----
  for (int f = wv; f < 128; f += 4) {
    const float* wr = c1w + f * 96;
    const float* hr = s_hand + e8 * 68 + kc;
    const float* gr = s_g + e8 * 36 + kc;
    float p = 0.f;
#pragma unroll
    for (int j = 0; j < 8; ++j) p += hr[8 * j] * wr[kc + 8 * j];
#pragma unroll
    for (int j = 0; j < 4; ++j) p += gr[8 * j] * wr[64 + kc + 8 * j];
    p += __shfl_xor(p, 1); p += __shfl_xor(p, 2); p += __shfl_xor(p, 4);
    if (kc == 0) s_ctx[e8 * 132 + f] = fmaxf(p + c1b[f], 0.f);
  }
  __syncthreads();

  // ---- P7: ctx2 = relu(c2 @ ctx) ----
  for (int f = wv; f < 128; f += 4) {
    const float* wr = c2w + f * 128 + kc;
    const float* xr2 = s_ctx + e8 * 132 + kc;
    float p = 0.f;
#pragma unroll
    for (int j = 0; j < 16; ++j) p += xr2[8 * j] * wr[8 * j];
    p += __shfl_xor(p, 1); p += __shfl_xor(p, 2); p += __shfl_xor(p, 4);
    if (kc == 0) s_ctx2[e8 * 132 + f] = fmaxf(p + c2b[f], 0.f);
  }
  __syncthreads();

  // ---- P8: s1a = ctx2 @ s1w[:,:128].T ----
  for (int f = wv; f < 64; f += 4) {
    const float* wr = s1w + f * 192 + kc;
    const float* xr2 = s_ctx2 + e8 * 132 + kc;
    float p = 0.f;
#pragma unroll
    for (int j = 0; j < 16; ++j) p += xr2[8 * j] * wr[8 * j];
    p += __shfl_xor(p, 1); p += __shfl_xor(p, 2); p += __shfl_xor(p, 4);
    if (kc == 0) s_s1a[e8 * 68 + f] = p;
  }
  __syncthreads();

  // ---- P9a: stage h[i=e*20+a][j] = relu(s1a[e][j] + s1bp[a][j]) as bf16 [160][66] ----
  for (int o = t; o < 5120; o += NT) {
    int i = o >> 5, j = (o & 31) * 2;
    int e = i / 20, a = i - e * 20;
    float2 sv = *(const float2*)(s_s1a + e * 68 + j);
    float2 bv = *(const float2*)(ws_s1bp + a * 64 + j);
    float v0 = fmaxf(sv.x + bv.x, 0.f), v1 = fmaxf(sv.y + bv.y, 0.f);
    *(u32*)(s_hbf + i * 66 + j) = pk2(v0, v1);
  }
  __syncthreads();

  // ---- P9b: score = relu(h @ s2w.T + s2b) . s3w + s3b via MFMA ----
  {
    const int kq = lw >> 4, rr = lw & 15;
    const int nv = num_valid[0];
    const float s3b0 = s3b[0];
    for (int mt = wv; mt < 10; mt += 4) {
      const int row = mt * 16 + rr;                                  // A row = lane&15
      short8v a0 = *(const short8v*)(s_hbf + row * 66 + kq * 8);
      short8v a1 = *(const short8v*)(s_hbf + row * 66 + 32 + kq * 8);
      float part[4] = {0.f, 0.f, 0.f, 0.f};
#pragma unroll
      for (int ntile = 0; ntile < 2; ++ntile) {
        const int m = ntile * 16 + rr;                               // C col = lane&15
        short8v b0 = *(const short8v*)(s2wbf + m * 64 + kq * 8);
        short8v b1 = *(const short8v*)(s2wbf + m * 64 + 32 + kq * 8);
        float bias = s2b[m];
        f32x4 acc = { bias, bias, bias, bias };
        acc = __builtin_amdgcn_mfma_f32_16x16x32_bf16(a0, b0, acc, 0, 0, 0);
        acc = __builtin_amdgcn_mfma_f32_16x16x32_bf16(a1, b1, acc, 0, 0, 0);
        const float w3 = s3w[m];
#pragma unroll
        for (int r = 0; r < 4; ++r) part[r] += fmaxf(acc[r], 0.f) * w3;
      }
#pragma unroll
      for (int r = 0; r < 4; ++r) {                                  // sum over 16 cols
        part[r] += __shfl_xor(part[r], 1);
        part[r] += __shfl_xor(part[r], 2);
        part[r] += __shfl_xor(part[r], 4);
        part[r] += __shfl_xor(part[r], 8);
      }
      if (rr == 0) {
        const int i0 = mt * 16 + kq * 4;                             // C row=(l>>4)*4+r
#pragma unroll
        for (int r = 0; r < 4; ++r) {
          int i = i0 + r;
          int a = i - (i / 20) * 20;
          out[base * 20 + i] = (a < nv) ? (part[r] + s3b0) : -1e8f;
        }
      }
    }
  }
}

extern "C" void kernel_launch(void* const* d_in, const int* in_sizes, int n_in,
                              void* d_out, int out_size, void* d_ws, size_t ws_size,
                              hipStream_t stream) {
  (void)in_sizes; (void)n_in; (void)out_size; (void)ws_size;
  float* out = (float*)d_out;
  float* ws = (float*)d_ws;

  hipLaunchKernelGGL(prep_kernel, dim3(1), dim3(256), 0, stream,
                     (const float*)d_in[6], (const int*)d_in[3], (const int*)d_in[4],
                     (const float*)d_in[19], (const float*)d_in[20],
                     (const float*)d_in[7], (const float*)d_in[21], ws);
  hipLaunchKernelGGL(policy_fused, dim3(32768 / TB), dim3(NT), 0, stream,
                     (const int*)d_in[0],  (const float*)d_in[1], (const int*)d_in[2],
                     (const int*)d_in[5],
                     (const float*)d_in[6],  (const float*)d_in[8],
                     (const float*)d_in[9],  (const float*)d_in[10],
                     (const float*)d_in[11], (const float*)d_in[12],
                     (const float*)d_in[13], (const float*)d_in[14],
                     (const float*)d_in[15], (const float*)d_in[16],
                     (const float*)d_in[17], (const float*)d_in[18],
                     (const float*)d_in[19], (const float*)d_in[22],
                     (const float*)d_in[23], (const float*)d_in[24],
                     ws, out);
}

// Round 7
// 147.701 us; speedup vs baseline: 6.7581x; 2.0236x over previous
//
#include <hip/hip_runtime.h>
#include <hip/hip_bf16.h>

#define NT 256
#define TB 8   // batch elements per block

typedef unsigned short u16;
typedef unsigned int u32;
typedef __attribute__((ext_vector_type(8))) short short8v;  // 8 bf16 (4 VGPRs)
typedef __attribute__((ext_vector_type(4))) float f32x4;

__device__ __forceinline__ float bf2f(u16 u) {
  union { u32 i; float f; } v; v.i = ((u32)u) << 16; return v.f;
}
__device__ __forceinline__ float2 up2(u32 p) {
  union { u32 i; float f; } a, b;
  a.i = p << 16; b.i = p & 0xffff0000u;
  return make_float2(a.f, b.f);
}
__device__ __forceinline__ u16 f2bf(float f) {
  union { float f; u32 i; } v; v.f = f;
  u32 r = v.i + 0x7fffu + ((v.i >> 16) & 1u);  // round-to-nearest-even
  return (u16)(r >> 16);
}
__device__ __forceinline__ u32 pk2(float a, float b) {
  return (u32)f2bf(a) | ((u32)f2bf(b) << 16);
}
__device__ __forceinline__ void up8(uint4 u, float* d) {
  float2 f;
  f = up2(u.x); d[0]=f.x; d[1]=f.y;
  f = up2(u.y); d[2]=f.x; d[3]=f.y;
  f = up2(u.z); d[4]=f.x; d[5]=f.y;
  f = up2(u.w); d[6]=f.x; d[7]=f.y;
}

// ws layout: f32 s1bp[20][64] @0 ; then u16 block at ws+1280:
//   wqkv [192][64] @0 | s2w [32][64] @12288 | ow [64][64] @14336 | g2w [32][64] @18432
//   c1w [128][96] @20480 | c2w [128][128] @32768 | s1wA [64][128] @49152
__global__ void prep_kernel(const float* __restrict__ emb, const int* __restrict__ act_idx,
                            const int* __restrict__ act_cnt, const float* __restrict__ s1w,
                            const float* __restrict__ s1b, const float* __restrict__ ipw,
                            const float* __restrict__ s2w, const float* __restrict__ ow,
                            const float* __restrict__ g2w, const float* __restrict__ c1w,
                            const float* __restrict__ c2w, float* __restrict__ ws) {
  __shared__ float s_arep[20][64];
  int t = threadIdx.x;
  for (int o = t; o < 20 * 64; o += 256) {
    int a = o >> 6, k = o & 63;
    int cnt = act_cnt[a];
    float sum = 0.f;
#pragma unroll
    for (int j = 0; j < 4; ++j)
      if (j < cnt) sum += emb[act_idx[a * 4 + j] * 64 + k];
    s_arep[a][k] = sum / (float)(cnt > 1 ? cnt : 1);
  }
  __syncthreads();
  for (int o = t; o < 20 * 64; o += 256) {
    int a = o >> 6, f = o & 63;
    const float* wr = s1w + f * 192 + 128;
    float acc = s1b[f];
#pragma unroll 8
    for (int k = 0; k < 64; ++k) acc += s_arep[a][k] * wr[k];
    ws[o] = acc;
  }
  u16* wbf = (u16*)(ws + 1280);
  for (int o = t; o < 12288; o += 256) wbf[o] = f2bf(ipw[o]);
  for (int o = t; o < 2048;  o += 256) wbf[12288 + o] = f2bf(s2w[o]);
  for (int o = t; o < 4096;  o += 256) wbf[14336 + o] = f2bf(ow[o]);
  for (int o = t; o < 2048;  o += 256) wbf[18432 + o] = f2bf(g2w[o]);
  for (int o = t; o < 12288; o += 256) wbf[20480 + o] = f2bf(c1w[o]);
  for (int o = t; o < 16384; o += 256) wbf[32768 + o] = f2bf(c2w[o]);
  for (int o = t; o < 8192;  o += 256) {
    int f = o >> 7, k = o & 127;
    wbf[49152 + o] = f2bf(s1w[f * 192 + k]);
  }
}

// LDS map (bytes), total 35488:
//  region A [0..25600):
//    x[64][72] u16 -> qkv[64][200] u16 (attention)
//    then MLP bf16: hxbf[16][72]@0 g1bf[16][72]@2304 ctxin[16][104]@4608
//                   ctxbf[16][136]@7936 ctx2bf[16][136]@12288
//    then hbf[160][72] u16 @0..23040 ; s1a f32 [8][68] @23040..25216
//  region B [25600..34816): sc f32 [2304] pad9 -> ah[64][72] u16
//  extras: cards@34816 invlen@35072 gs@35104
__global__ __launch_bounds__(NT, 4) void policy_fused(
    const int* __restrict__ hand_cards, const float* __restrict__ game_state,
    const int* __restrict__ hand_size, const int* __restrict__ num_valid,
    const float* __restrict__ emb, const float* __restrict__ ipb,
    const float* __restrict__ ob, const float* __restrict__ g1w,
    const float* __restrict__ g1b, const float* __restrict__ g2b,
    const float* __restrict__ c1b, const float* __restrict__ c2b,
    const float* __restrict__ s2b, const float* __restrict__ s3w,
    const float* __restrict__ s3b, const float* __restrict__ ws,
    float* __restrict__ out)
{
  __shared__ __align__(16) unsigned char s_raw[35488];
  u16*   s_x     = (u16*)s_raw;                 // [64][72]
  u16*   s_qkv   = (u16*)s_raw;                 // [64][200]
  float* s_sc    = (float*)(s_raw + 25600);     // [2304] pad 9
  u16*   s_ah    = (u16*)(s_raw + 25600);       // [64][72]
  u16*   s_hxbf  = (u16*)(s_raw + 0);           // [16][72]
  u16*   s_g1bf  = (u16*)(s_raw + 2304);        // [16][72]
  u16*   s_ctxin = (u16*)(s_raw + 4608);        // [16][104] hand|g
  u16*   s_ctxbf = (u16*)(s_raw + 7936);        // [16][136]
  u16*   s_ctx2bf= (u16*)(s_raw + 12288);       // [16][136]
  u16*   s_hbf   = (u16*)s_raw;                 // [160][72] (P9)
  float* s_s1a   = (float*)(s_raw + 23040);     // [8][68]
  int*   s_cards  = (int*)(s_raw + 34816);      // [64]
  float* s_invlen = (float*)(s_raw + 35072);    // [8]
  float* s_gs    = (float*)(s_raw + 35104);     // [8][12]

  const float* ws_s1bp = ws;                         // [20][64]
  const u16* wbf    = (const u16*)(ws + 1280);
  const u16* wqkv   = wbf;                           // [192][64]
  const u16* s2wbf  = wbf + 12288;                   // [32][64]
  const u16* owbf   = wbf + 14336;                   // [64][64]
  const u16* g2wbf  = wbf + 18432;                   // [32][64]
  const u16* c1wbf  = wbf + 20480;                   // [128][96]
  const u16* c2wbf  = wbf + 32768;                   // [128][128]
  const u16* s1wbf  = wbf + 49152;                   // [64][128]

  const int t = threadIdx.x;
  const int base = blockIdx.x * TB;
  const int lw = t & 63, wv = t >> 6;
  const int kq = lw >> 4, rr = lw & 15;   // MFMA: A row / C col = rr; k-chunk & C row-group = kq
  const int row0 = kq * 4;

  // ---- P0a ----
  if (t < 64) s_cards[t] = hand_cards[base * 8 + t];
  if (t < TB) { int hs = hand_size[base + t]; s_invlen[t] = 1.0f / (float)(hs > 1 ? hs : 1); }
  if (t >= 64 && t < 64 + TB * 12) {
    int i = t - 64; s_gs[(i / 12) * 12 + (i % 12)] = game_state[(base + i / 12) * 12 + i % 12];
  }
  __syncthreads();

  // ---- P0b: gather x = emb[cards] -> bf16 LDS ----
  {
    int es = t >> 2, k0 = (t & 3) * 16;
    const float* src = emb + s_cards[es] * 64 + k0;
    float4 v0 = *(const float4*)(src);
    float4 v1 = *(const float4*)(src + 4);
    float4 v2 = *(const float4*)(src + 8);
    float4 v3 = *(const float4*)(src + 12);
    uint4 pa = make_uint4(pk2(v0.x,v0.y), pk2(v0.z,v0.w), pk2(v1.x,v1.y), pk2(v1.z,v1.w));
    uint4 pb = make_uint4(pk2(v2.x,v2.y), pk2(v2.z,v2.w), pk2(v3.x,v3.y), pk2(v3.z,v3.w));
    *(uint4*)(s_x + es * 72 + k0) = pa;
    *(uint4*)(s_x + es * 72 + k0 + 8) = pb;
  }
  __syncthreads();

  // ---- P1: qkv = x @ ipw.T + ipb via MFMA ----
  {
    const int tok = wv * 16 + rr;
    short8v a0 = *(const short8v*)(s_x + tok * 72 + kq * 8);
    short8v a1 = *(const short8v*)(s_x + tok * 72 + 32 + kq * 8);
    __syncthreads();   // A frags in regs; qkv may overwrite x
    const int trow = wv * 16 + row0;
    for (int n = 0; n < 12; ++n) {
      const int f = n * 16 + rr;
      short8v b0 = *(const short8v*)(wqkv + f * 64 + kq * 8);
      short8v b1 = *(const short8v*)(wqkv + f * 64 + 32 + kq * 8);
      float bias = ipb[f];
      f32x4 acc = { bias, bias, bias, bias };
      acc = __builtin_amdgcn_mfma_f32_16x16x32_bf16(a0, b0, acc, 0, 0, 0);
      acc = __builtin_amdgcn_mfma_f32_16x16x32_bf16(a1, b1, acc, 0, 0, 0);
#pragma unroll
      for (int r = 0; r < 4; ++r)
        s_qkv[(trow + r) * 200 + f] = f2bf(acc[r]);
    }
  }
  __syncthreads();

  // ---- P2: masked scaled scores + softmax ----
  {
    int e = t >> 5, h = (t >> 3) & 3, q = t & 7;
    const u16* qrow = s_qkv + (e * 8 + q) * 200 + h * 16;
    float qr[16];
    up8(*(const uint4*)(qrow), qr);
    up8(*(const uint4*)(qrow + 8), qr + 8);
    float sc[8];
#pragma unroll
    for (int kk = 0; kk < 8; ++kk) {
      const u16* krow = s_qkv + (e * 8 + kk) * 200 + 64 + h * 16;
      float kr[16];
      up8(*(const uint4*)(krow), kr);
      up8(*(const uint4*)(krow + 8), kr + 8);
      float a0 = 0.f;
#pragma unroll
      for (int d = 0; d < 16; ++d) a0 += qr[d] * kr[d];
      sc[kk] = (s_cards[e * 8 + kk] != 0) ? a0 * 0.25f : -1e9f;
    }
    float m = sc[0];
#pragma unroll
    for (int kk = 1; kk < 8; ++kk) m = fmaxf(m, sc[kk]);
    float ssum = 0.f;
#pragma unroll
    for (int kk = 0; kk < 8; ++kk) { sc[kk] = __expf(sc[kk] - m); ssum += sc[kk]; }
    float inv = 1.f / ssum;
    float* dst = s_sc + ((e * 4 + h) * 8 + q) * 9;
#pragma unroll
    for (int kk = 0; kk < 8; ++kk) dst[kk] = sc[kk] * inv;
  }
  __syncthreads();

  // ---- P4: ah = attn @ V ; ah overlays sc ----
  {
    int es = lw, h = wv;
    int e = es >> 3, q = es & 7;
    const float* pr = s_sc + ((e * 4 + h) * 8 + q) * 9;
    float p[8];
#pragma unroll
    for (int kk = 0; kk < 8; ++kk) p[kk] = pr[kk];
    __syncthreads();
    float acc[16];
#pragma unroll
    for (int d = 0; d < 16; ++d) acc[d] = 0.f;
#pragma unroll
    for (int kk = 0; kk < 8; ++kk) {
      const u16* vrow = s_qkv + (e * 8 + kk) * 200 + 128 + h * 16;
      float vv[16];
      up8(*(const uint4*)(vrow), vv);
      up8(*(const uint4*)(vrow + 8), vv + 8);
#pragma unroll
      for (int d = 0; d < 16; ++d) acc[d] += p[kk] * vv[d];
    }
    uint4 oa = make_uint4(pk2(acc[0],acc[1]), pk2(acc[2],acc[3]), pk2(acc[4],acc[5]), pk2(acc[6],acc[7]));
    uint4 oc = make_uint4(pk2(acc[8],acc[9]), pk2(acc[10],acc[11]), pk2(acc[12],acc[13]), pk2(acc[14],acc[15]));
    *(uint4*)(s_ah + es * 72 + h * 16) = oa;
    *(uint4*)(s_ah + es * 72 + h * 16 + 8) = oc;
  }
  __syncthreads();

  // ---- P5a: hxbf = sum_q ah (bf16) ; g1 MLP -> g1bf ----
  {
    int e = t >> 5, k2 = (t & 31) * 2;
    float s0 = 0.f, s1 = 0.f;
#pragma unroll
    for (int q = 0; q < 8; ++q) {
      float2 f = up2(*(const u32*)(s_ah + (e * 8 + q) * 72 + k2));
      s0 += f.x; s1 += f.y;
    }
    *(u32*)(s_hxbf + e * 72 + k2) = pk2(s0, s1);
  }
  for (int o = t; o < TB * 64; o += NT) {
    int e = o >> 6, f = o & 63;
    float acc = g1b[f];
#pragma unroll
    for (int k = 0; k < 12; ++k) acc += s_gs[e * 12 + k] * g1w[f * 12 + k];
    s_g1bf[e * 72 + f] = f2bf(fmaxf(acc, 0.f));
  }
  __syncthreads();

  // ---- P5b: hand = (hx@ow.T + 8*ob)*invlen -> ctxin[:, :64] ; g2 -> ctxin[:, 64:96] ----
  {
    short8v a0 = *(const short8v*)(s_hxbf + rr * 72 + kq * 8);
    short8v a1 = *(const short8v*)(s_hxbf + rr * 72 + 32 + kq * 8);
    const int f = wv * 16 + rr;
    short8v b0 = *(const short8v*)(owbf + f * 64 + kq * 8);
    short8v b1 = *(const short8v*)(owbf + f * 64 + 32 + kq * 8);
    float bias = 8.f * ob[f];
    f32x4 acc = { bias, bias, bias, bias };
    acc = __builtin_amdgcn_mfma_f32_16x16x32_bf16(a0, b0, acc, 0, 0, 0);
    acc = __builtin_amdgcn_mfma_f32_16x16x32_bf16(a1, b1, acc, 0, 0, 0);
#pragma unroll
    for (int r = 0; r < 4; ++r) {
      int row = row0 + r;
      if (row < 8) s_ctxin[row * 104 + f] = f2bf(acc[r] * s_invlen[row]);
    }
    if (wv < 2) {
      short8v g0 = *(const short8v*)(s_g1bf + rr * 72 + kq * 8);
      short8v g1v = *(const short8v*)(s_g1bf + rr * 72 + 32 + kq * 8);
      const int f2 = wv * 16 + rr;
      short8v c0 = *(const short8v*)(g2wbf + f2 * 64 + kq * 8);
      short8v c1 = *(const short8v*)(g2wbf + f2 * 64 + 32 + kq * 8);
      float b2 = g2b[f2];
      f32x4 acc2 = { b2, b2, b2, b2 };
      acc2 = __builtin_amdgcn_mfma_f32_16x16x32_bf16(g0, c0, acc2, 0, 0, 0);
      acc2 = __builtin_amdgcn_mfma_f32_16x16x32_bf16(g1v, c1, acc2, 0, 0, 0);
#pragma unroll
      for (int r = 0; r < 4; ++r) {
        int row = row0 + r;
        if (row < 8) s_ctxin[row * 104 + 64 + f2] = f2bf(fmaxf(acc2[r], 0.f));
      }
    }
  }
  __syncthreads();

  // ---- P6: ctx = relu(ctxin @ c1.T + c1b), K=96 N=128 ----
  {
    short8v a0 = *(const short8v*)(s_ctxin + rr * 104 + kq * 8);
    short8v a1 = *(const short8v*)(s_ctxin + rr * 104 + 32 + kq * 8);
    short8v a2 = *(const short8v*)(s_ctxin + rr * 104 + 64 + kq * 8);
#pragma unroll
    for (int sub = 0; sub < 2; ++sub) {
      const int f = (wv * 2 + sub) * 16 + rr;
      short8v b0 = *(const short8v*)(c1wbf + f * 96 + kq * 8);
      short8v b1 = *(const short8v*)(c1wbf + f * 96 + 32 + kq * 8);
      short8v b2 = *(const short8v*)(c1wbf + f * 96 + 64 + kq * 8);
      float bias = c1b[f];
      f32x4 acc = { bias, bias, bias, bias };
      acc = __builtin_amdgcn_mfma_f32_16x16x32_bf16(a0, b0, acc, 0, 0, 0);
      acc = __builtin_amdgcn_mfma_f32_16x16x32_bf16(a1, b1, acc, 0, 0, 0);
      acc = __builtin_amdgcn_mfma_f32_16x16x32_bf16(a2, b2, acc, 0, 0, 0);
#pragma unroll
      for (int r = 0; r < 4; ++r) {
        int row = row0 + r;
        if (row < 8) s_ctxbf[row * 136 + f] = f2bf(fmaxf(acc[r], 0.f));
      }
    }
  }
  __syncthreads();

  // ---- P7: ctx2 = relu(ctx @ c2.T + c2b), K=128 N=128 ----
  {
    short8v a0 = *(const short8v*)(s_ctxbf + rr * 136 + kq * 8);
    short8v a1 = *(const short8v*)(s_ctxbf + rr * 136 + 32 + kq * 8);
    short8v a2 = *(const short8v*)(s_ctxbf + rr * 136 + 64 + kq * 8);
    short8v a3 = *(const short8v*)(s_ctxbf + rr * 136 + 96 + kq * 8);
#pragma unroll
    for (int sub = 0; sub < 2; ++sub) {
      const int f = (wv * 2 + sub) * 16 + rr;
      short8v b0 = *(const short8v*)(c2wbf + f * 128 + kq * 8);
      short8v b1 = *(const short8v*)(c2wbf + f * 128 + 32 + kq * 8);
      short8v b2 = *(const short8v*)(c2wbf + f * 128 + 64 + kq * 8);
      short8v b3 = *(const short8v*)(c2wbf + f * 128 + 96 + kq * 8);
      float bias = c2b[f];
      f32x4 acc = { bias, bias, bias, bias };
      acc = __builtin_amdgcn_mfma_f32_16x16x32_bf16(a0, b0, acc, 0, 0, 0);
      acc = __builtin_amdgcn_mfma_f32_16x16x32_bf16(a1, b1, acc, 0, 0, 0);
      acc = __builtin_amdgcn_mfma_f32_16x16x32_bf16(a2, b2, acc, 0, 0, 0);
      acc = __builtin_amdgcn_mfma_f32_16x16x32_bf16(a3, b3, acc, 0, 0, 0);
#pragma unroll
      for (int r = 0; r < 4; ++r) {
        int row = row0 + r;
        if (row < 8) s_ctx2bf[row * 136 + f] = f2bf(fmaxf(acc[r], 0.f));
      }
    }
  }
  __syncthreads();

  // ---- P8: s1a = ctx2 @ s1w[:,:128].T (f32 out), K=128 N=64 ----
  {
    short8v a0 = *(const short8v*)(s_ctx2bf + rr * 136 + kq * 8);
    short8v a1 = *(const short8v*)(s_ctx2bf + rr * 136 + 32 + kq * 8);
    short8v a2 = *(const short8v*)(s_ctx2bf + rr * 136 + 64 + kq * 8);
    short8v a3 = *(const short8v*)(s_ctx2bf + rr * 136 + 96 + kq * 8);
    const int f = wv * 16 + rr;
    short8v b0 = *(const short8v*)(s1wbf + f * 128 + kq * 8);
    short8v b1 = *(const short8v*)(s1wbf + f * 128 + 32 + kq * 8);
    short8v b2 = *(const short8v*)(s1wbf + f * 128 + 64 + kq * 8);
    short8v b3 = *(const short8v*)(s1wbf + f * 128 + 96 + kq * 8);
    f32x4 acc = { 0.f, 0.f, 0.f, 0.f };
    acc = __builtin_amdgcn_mfma_f32_16x16x32_bf16(a0, b0, acc, 0, 0, 0);
    acc = __builtin_amdgcn_mfma_f32_16x16x32_bf16(a1, b1, acc, 0, 0, 0);
    acc = __builtin_amdgcn_mfma_f32_16x16x32_bf16(a2, b2, acc, 0, 0, 0);
    acc = __builtin_amdgcn_mfma_f32_16x16x32_bf16(a3, b3, acc, 0, 0, 0);
#pragma unroll
    for (int r = 0; r < 4; ++r) {
      int row = row0 + r;
      if (row < 8) s_s1a[row * 68 + f] = acc[r];
    }
  }
  __syncthreads();

  // ---- P9a: h[i=e*20+a][j] = relu(s1a[e][j] + s1bp[a][j]) -> bf16 [160][72] ----
  for (int o = t; o < 5120; o += NT) {
    int i = o >> 5, j = (o & 31) * 2;
    int e = i / 20, a = i - e * 20;
    float2 sv = *(const float2*)(s_s1a + e * 68 + j);
    float2 bv = *(const float2*)(ws_s1bp + a * 64 + j);
    float v0 = fmaxf(sv.x + bv.x, 0.f), v1 = fmaxf(sv.y + bv.y, 0.f);
    *(u32*)(s_hbf + i * 72 + j) = pk2(v0, v1);
  }
  __syncthreads();

  // ---- P9b: score = relu(h @ s2w.T + s2b) . s3w + s3b via MFMA ----
  {
    const int nv = num_valid[0];
    const float s3b0 = s3b[0];
    for (int mt = wv; mt < 10; mt += 4) {
      const int row = mt * 16 + rr;
      short8v a0 = *(const short8v*)(s_hbf + row * 72 + kq * 8);
      short8v a1 = *(const short8v*)(s_hbf + row * 72 + 32 + kq * 8);
      float part[4] = {0.f, 0.f, 0.f, 0.f};
#pragma unroll
      for (int ntile = 0; ntile < 2; ++ntile) {
        const int m = ntile * 16 + rr;
        short8v b0 = *(const short8v*)(s2wbf + m * 64 + kq * 8);
        short8v b1 = *(const short8v*)(s2wbf + m * 64 + 32 + kq * 8);
        float bias = s2b[m];
        f32x4 acc = { bias, bias, bias, bias };
        acc = __builtin_amdgcn_mfma_f32_16x16x32_bf16(a0, b0, acc, 0, 0, 0);
        acc = __builtin_amdgcn_mfma_f32_16x16x32_bf16(a1, b1, acc, 0, 0, 0);
        const float w3 = s3w[m];
#pragma unroll
        for (int r = 0; r < 4; ++r) part[r] += fmaxf(acc[r], 0.f) * w3;
      }
#pragma unroll
      for (int r = 0; r < 4; ++r) {
        part[r] += __shfl_xor(part[r], 1);
        part[r] += __shfl_xor(part[r], 2);
        part[r] += __shfl_xor(part[r], 4);
        part[r] += __shfl_xor(part[r], 8);
      }
      if (rr == 0) {
        const int i0 = mt * 16 + kq * 4;
#pragma unroll
        for (int r = 0; r < 4; ++r) {
          int i = i0 + r;
          int a = i - (i / 20) * 20;
          out[base * 20 + i] = (a < nv) ? (part[r] + s3b0) : -1e8f;
        }
      }
    }
  }
}

extern "C" void kernel_launch(void* const* d_in, const int* in_sizes, int n_in,
                              void* d_out, int out_size, void* d_ws, size_t ws_size,
                              hipStream_t stream) {
  (void)in_sizes; (void)n_in; (void)out_size; (void)ws_size;
  float* out = (float*)d_out;
  float* ws = (float*)d_ws;

  hipLaunchKernelGGL(prep_kernel, dim3(1), dim3(256), 0, stream,
                     (const float*)d_in[6], (const int*)d_in[3], (const int*)d_in[4],
                     (const float*)d_in[19], (const float*)d_in[20],
                     (const float*)d_in[7], (const float*)d_in[21],
                     (const float*)d_in[9], (const float*)d_in[13],
                     (const float*)d_in[15], (const float*)d_in[17], ws);
  hipLaunchKernelGGL(policy_fused, dim3(32768 / TB), dim3(NT), 0, stream,
                     (const int*)d_in[0],  (const float*)d_in[1], (const int*)d_in[2],
                     (const int*)d_in[5],
                     (const float*)d_in[6],  (const float*)d_in[8],
                     (const float*)d_in[10], (const float*)d_in[11],
                     (const float*)d_in[12], (const float*)d_in[14],
                     (const float*)d_in[16], (const float*)d_in[18],
                     (const float*)d_in[22], (const float*)d_in[23],
                     (const float*)d_in[24], ws, out);
}